// Round 2
// baseline (1343.543 us; speedup 1.0000x reference)
//
#include <hip/hip_runtime.h>

#define NN 100000
#define NE 800000

typedef _Float16 f16;
typedef __attribute__((ext_vector_type(4))) _Float16 f16x4;
typedef __attribute__((ext_vector_type(8))) _Float16 f16x8;
typedef __attribute__((ext_vector_type(4))) float f32x4;

struct EPtrs { const int* s[9]; const int* d[9]; };

// ---------------- prep: combined weights ----------------
// wc0: 18x16 f32 (rows 0-5 Wn0, 6-11 Wn1, 12-17 Wr0+Wr1), bc0 = b0[0]+b0[1]
// wc1: 48x32 f32 (rows 0-15 Wn0, 16-31 Wn1, 32-47 Wr0+Wr1+P1), bc1
// b2frag: 256x64 weights as f16 pre-swizzled into MFMA B-fragment order:
//   idx = ((kt*4+nt)*64 + lane)*8 + j  holds  Wc2[kt*32+(lane>>4)*8+j][nt*16+(lane&15)]
__global__ __launch_bounds__(256) void prep_weights(
    const float* __restrict__ W0n, const float* __restrict__ W0r, const float* __restrict__ b0,
    const float* __restrict__ W1n, const float* __restrict__ W1r, const float* __restrict__ b1,
    const float* __restrict__ P1,  const float* __restrict__ pb1,
    const float* __restrict__ W2n, const float* __restrict__ W2r, const float* __restrict__ b2,
    const float* __restrict__ P2,  const float* __restrict__ pb2,
    float* __restrict__ wc0, float* __restrict__ bc0,
    float* __restrict__ wc1, float* __restrict__ bc1,
    f16*   __restrict__ b2frag, float* __restrict__ bc2)
{
    int tid = threadIdx.x;
    for (int t = tid; t < 18 * 16; t += 256) {
        int row = t >> 4, col = t & 15;
        float v;
        if (row < 6)       v = W0n[row * 16 + col];
        else if (row < 12) v = W0n[96 + (row - 6) * 16 + col];
        else               v = W0r[(row - 12) * 16 + col] + W0r[96 + (row - 12) * 16 + col];
        wc0[t] = v;
    }
    for (int t = tid; t < 16; t += 256) bc0[t] = b0[t] + b0[16 + t];

    for (int t = tid; t < 48 * 32; t += 256) {
        int row = t >> 5, col = t & 31;
        float v;
        if (row < 16)      v = W1n[row * 32 + col];
        else if (row < 32) v = W1n[512 + (row - 16) * 32 + col];
        else { int rr = row - 32; v = W1r[rr * 32 + col] + W1r[512 + rr * 32 + col] + P1[rr * 32 + col]; }
        wc1[t] = v;
    }
    for (int t = tid; t < 32; t += 256) bc1[t] = b1[t] + b1[32 + t] + pb1[t];

    for (int t = tid; t < 256 * 64; t += 256) {
        int j = t & 7, lane = (t >> 3) & 63, ntk = t >> 9;
        int nt = ntk & 3, kt = ntk >> 2;
        int k = kt * 32 + (lane >> 4) * 8 + j;
        int n = nt * 16 + (lane & 15);
        float v;
        if (k < 224) v = W2n[k * 64 + n];
        else {
            int rr = k - 224;
            v = P2[rr * 64 + n];
            #pragma unroll
            for (int r = 0; r < 7; ++r) v += W2r[r * 2048 + rr * 64 + n];
        }
        b2frag[t] = (f16)v;
    }
    for (int t = tid; t < 64; t += 256) {
        float v = pb2[t];
        #pragma unroll
        for (int r = 0; r < 7; ++r) v += b2[r * 64 + t];
        bc2[t] = v;
    }
}

// ---------------- CSR build ----------------
__global__ __launch_bounds__(256) void hist9(EPtrs ep, int* __restrict__ deg)
{
    int r = blockIdx.y;
    int e = blockIdx.x * 256 + threadIdx.x;   // grid.x*256 == NE exactly
    atomicAdd(&deg[r * NN + ep.d[r][e]], 1);
}

// exclusive scan of deg -> off, one block (1024 thr) per relation
__global__ __launch_bounds__(1024) void scan9(const int* __restrict__ deg, int* __restrict__ off)
{
    int r = blockIdx.x;
    int tid = threadIdx.x, lane = tid & 63, wid = tid >> 6;
    __shared__ int woff[16];
    __shared__ int stot;
    int carry = 0;
    for (int base = 0; base < NN; base += 1024) {
        int i = base + tid;
        int v = (i < NN) ? deg[r * NN + i] : 0;
        int incl = v;
        #pragma unroll
        for (int ofs = 1; ofs < 64; ofs <<= 1) {
            int t = __shfl_up(incl, ofs, 64);
            if (lane >= ofs) incl += t;
        }
        if (lane == 63) woff[wid] = incl;
        __syncthreads();
        if (tid < 16) {
            int wv = woff[tid];
            int winc = wv;
            #pragma unroll
            for (int ofs = 1; ofs < 16; ofs <<= 1) {
                int t = __shfl_up(winc, ofs, 64);
                if (tid >= ofs) winc += t;
            }
            woff[tid] = winc - wv;
            if (tid == 15) stot = winc;
        }
        __syncthreads();
        int excl = incl - v + woff[wid] + carry;
        if (i < NN) off[r * NN + i] = excl;
        carry += stot;
        __syncthreads();
    }
}

// fill: bumps off[r][n] to row end; eidx gets src ids grouped by dst
__global__ __launch_bounds__(256) void fill9(EPtrs ep, int* __restrict__ off, int* __restrict__ eidx)
{
    int r = blockIdx.y;
    int e = blockIdx.x * 256 + threadIdx.x;
    int dv = ep.d[r][e];
    int pos = atomicAdd(&off[r * NN + dv], 1);
    eidx[(size_t)r * NE + pos] = ep.s[r][e];
}

// ---------------- layer 0 fused gather+transform: x(6) -> h0h(16 f16) ----------------
__global__ __launch_bounds__(256) void t0f(const float* __restrict__ x,
                                           const int* __restrict__ deg, const int* __restrict__ off,
                                           const int* __restrict__ eidx,
                                           const float* __restrict__ wc0, const float* __restrict__ bc0,
                                           f16* __restrict__ h0h)
{
    __shared__ float sw[288 + 16];
    for (int t = threadIdx.x; t < 304; t += 256) sw[t] = (t < 288) ? wc0[t] : bc0[t - 288];
    __syncthreads();
    int n = blockIdx.x * 256 + threadIdx.x;
    if (n >= NN) return;
    float acc[16];
    #pragma unroll
    for (int j = 0; j < 16; ++j) acc[j] = sw[288 + j];
    float xv[6];
    {
        const float2* xp = reinterpret_cast<const float2*>(x + (size_t)n * 6);
        float2 a = xp[0], b = xp[1], c = xp[2];
        xv[0] = a.x; xv[1] = a.y; xv[2] = b.x; xv[3] = b.y; xv[4] = c.x; xv[5] = c.y;
    }
    #pragma unroll
    for (int r = 0; r < 2; ++r) {
        float m[6] = {0, 0, 0, 0, 0, 0};
        int e1 = off[r * NN + n];
        int e0 = e1 - deg[r * NN + n];
        for (int e = e0; e < e1; ++e) {
            int s = eidx[(size_t)r * NE + e];
            const float2* sp = reinterpret_cast<const float2*>(x + (size_t)s * 6);
            float2 a = sp[0], b = sp[1], c = sp[2];
            m[0] += a.x; m[1] += a.y; m[2] += b.x; m[3] += b.y; m[4] += c.x; m[5] += c.y;
        }
        #pragma unroll
        for (int k = 0; k < 6; ++k) {
            float s = m[k];
            #pragma unroll
            for (int j = 0; j < 16; ++j) acc[j] = fmaf(s, sw[(r * 6 + k) * 16 + j], acc[j]);
        }
    }
    #pragma unroll
    for (int k = 0; k < 6; ++k) {
        float s = xv[k];
        #pragma unroll
        for (int j = 0; j < 16; ++j) acc[j] = fmaf(s, sw[(12 + k) * 16 + j], acc[j]);
    }
    f16x8 o0, o1;
    #pragma unroll
    for (int j = 0; j < 8; ++j) { o0[j] = (f16)acc[j]; o1[j] = (f16)acc[8 + j]; }
    f16x8* op = reinterpret_cast<f16x8*>(h0h + (size_t)n * 16);
    op[0] = o0; op[1] = o1;
}

// ---------------- layer 1 fused: h0h(16) -> h1 (f16, into m2cat slot 224) ----------------
__global__ __launch_bounds__(256) void t1f(const f16* __restrict__ h0h,
                                           const int* __restrict__ deg, const int* __restrict__ off,
                                           const int* __restrict__ eidx,
                                           const float* __restrict__ wc1, const float* __restrict__ bc1,
                                           f16* __restrict__ m2cat)
{
    __shared__ float sw[1536 + 32];
    for (int t = threadIdx.x; t < 1568; t += 256) sw[t] = (t < 1536) ? wc1[t] : bc1[t - 1536];
    __syncthreads();
    int n = blockIdx.x * 256 + threadIdx.x;
    if (n >= NN) return;
    float acc[32];
    #pragma unroll
    for (int j = 0; j < 32; ++j) acc[j] = sw[1536 + j];
    #pragma unroll
    for (int r = 0; r < 2; ++r) {
        float m[16];
        #pragma unroll
        for (int k = 0; k < 16; ++k) m[k] = 0.f;
        int e1 = off[r * NN + n];
        int e0 = e1 - deg[r * NN + n];
        for (int e = e0; e < e1; ++e) {
            int s = eidx[(size_t)r * NE + e];
            const f16x8* sp = reinterpret_cast<const f16x8*>(h0h + (size_t)s * 16);
            f16x8 a = sp[0], b = sp[1];
            #pragma unroll
            for (int k = 0; k < 8; ++k) { m[k] += (float)a[k]; m[8 + k] += (float)b[k]; }
        }
        #pragma unroll
        for (int k = 0; k < 16; ++k) {
            float s = m[k];
            #pragma unroll
            for (int j = 0; j < 32; ++j) acc[j] = fmaf(s, sw[(r * 16 + k) * 32 + j], acc[j]);
        }
    }
    {
        const f16x8* hp = reinterpret_cast<const f16x8*>(h0h + (size_t)n * 16);
        f16x8 a = hp[0], b = hp[1];
        #pragma unroll
        for (int k = 0; k < 8; ++k) {
            float s0 = (float)a[k], s1 = (float)b[k];
            #pragma unroll
            for (int j = 0; j < 32; ++j)
                acc[j] = fmaf(s0, sw[(32 + k) * 32 + j], fmaf(s1, sw[(40 + k) * 32 + j], acc[j]));
        }
    }
    f16x8* op = reinterpret_cast<f16x8*>(m2cat + (size_t)n * 256 + 224);
    #pragma unroll
    for (int q = 0; q < 4; ++q) {
        f16x8 o;
        #pragma unroll
        for (int j = 0; j < 8; ++j) o[j] = (f16)fmaxf(acc[q * 8 + j], 0.f);
        op[q] = o;
    }
}

// ---------------- layer 2 gather: 8 lanes/node, h1 slots -> msg slots of m2cat ----------------
__global__ __launch_bounds__(256) void g2(const int* __restrict__ deg, const int* __restrict__ off,
                                          const int* __restrict__ eidx, f16* __restrict__ m2cat)
{
    int r = blockIdx.y;                         // 0..6 -> edge list r+2
    int t = blockIdx.x * 256 + threadIdx.x;     // 3125*256 == NN*8 exactly
    int node = t >> 3, l = t & 7;
    int L = r + 2;
    int d = deg[L * NN + node];
    int e1 = off[L * NN + node];
    int e0 = e1 - d;
    float a0 = 0.f, a1 = 0.f, a2 = 0.f, a3 = 0.f;
    for (int e = e0; e < e1; ++e) {
        int s = eidx[(size_t)L * NE + e];
        f16x4 v = *reinterpret_cast<const f16x4*>(m2cat + (size_t)s * 256 + 224 + l * 4);
        a0 += (float)v[0]; a1 += (float)v[1]; a2 += (float)v[2]; a3 += (float)v[3];
    }
    float sc = (r == 2 || r == 3 || r == 6) ? (1.0f / (float)max(d, 1)) : 1.0f;
    f16x4 o;
    o[0] = (f16)(a0 * sc); o[1] = (f16)(a1 * sc); o[2] = (f16)(a2 * sc); o[3] = (f16)(a3 * sc);
    *reinterpret_cast<f16x4*>(m2cat + (size_t)node * 256 + r * 32 + l * 4) = o;
}

// ---------------- layer 2 transform: MFMA GEMM [100000x256] x [256x64] + bias, relu ----------------
// A: m2cat rows (f16). B: b2frag resident in registers. C layout (verified):
// col = lane&15, row = (lane>>4)*4 + reg.  A layout: m = lane&15, k = (lane>>4)*8 + j.
__global__ __launch_bounds__(256) void t2(const f16* __restrict__ m2cat, const f16* __restrict__ b2frag,
                                          const float* __restrict__ bc2, float* __restrict__ out)
{
    int lane = threadIdx.x & 63;
    int gw = blockIdx.x * 4 + (threadIdx.x >> 6);
    int NW = gridDim.x * 4;
    int quad = lane >> 4, col0 = lane & 15;

    f16x8 bf[32];
    #pragma unroll
    for (int i = 0; i < 32; ++i)
        bf[i] = *reinterpret_cast<const f16x8*>(b2frag + ((size_t)i * 64 + lane) * 8);
    float bcv[4];
    #pragma unroll
    for (int nt = 0; nt < 4; ++nt) bcv[nt] = bc2[nt * 16 + col0];

    for (int mt = gw; mt < NN / 16; mt += NW) {
        const f16* arow = m2cat + ((size_t)(mt * 16 + col0)) * 256 + quad * 8;
        f16x8 af[8];
        #pragma unroll
        for (int kt = 0; kt < 8; ++kt)
            af[kt] = *reinterpret_cast<const f16x8*>(arow + kt * 32);
        f32x4 acc[4];
        #pragma unroll
        for (int nt = 0; nt < 4; ++nt) acc[nt] = (f32x4){0.f, 0.f, 0.f, 0.f};
        #pragma unroll
        for (int kt = 0; kt < 8; ++kt) {
            #pragma unroll
            for (int nt = 0; nt < 4; ++nt)
                acc[nt] = __builtin_amdgcn_mfma_f32_16x16x32_f16(af[kt], bf[kt * 4 + nt], acc[nt], 0, 0, 0);
        }
        #pragma unroll
        for (int nt = 0; nt < 4; ++nt) {
            #pragma unroll
            for (int i = 0; i < 4; ++i) {
                int row = mt * 16 + quad * 4 + i;
                out[(size_t)row * 64 + nt * 16 + col0] = fmaxf(acc[nt][i] + bcv[nt], 0.f);
            }
        }
    }
}

// ---------------- launch ----------------
extern "C" void kernel_launch(void* const* d_in, const int* in_sizes, int n_in,
                              void* d_out, int out_size, void* d_ws, size_t ws_size,
                              hipStream_t stream)
{
    const float* x = (const float*)d_in[0];
    EPtrs ep;
    for (int i = 0; i < 9; ++i) { const int* p = (const int*)d_in[1 + i]; ep.s[i] = p; ep.d[i] = p + NE; }
    const float* W0n = (const float*)d_in[10]; const float* W0r = (const float*)d_in[11];
    const float* b0  = (const float*)d_in[12];
    const float* W1n = (const float*)d_in[13]; const float* W1r = (const float*)d_in[14];
    const float* b1  = (const float*)d_in[15];
    const float* P1  = (const float*)d_in[16]; const float* pb1 = (const float*)d_in[17];
    const float* W2n = (const float*)d_in[18]; const float* W2r = (const float*)d_in[19];
    const float* b2  = (const float*)d_in[20];
    const float* P2  = (const float*)d_in[21]; const float* pb2 = (const float*)d_in[22];
    float* out = (float*)d_out;
    char* ws = (char*)d_ws;

    size_t off_b = 0;
    auto alloc = [&](size_t b) { size_t o = off_b; off_b += (b + 255) & ~(size_t)255; return o; };
    size_t o_wc0 = alloc(288 * 4);   size_t o_bc0 = alloc(16 * 4);
    size_t o_wc1 = alloc(1536 * 4);  size_t o_bc1 = alloc(32 * 4);
    size_t o_b2f = alloc(16384 * 2); size_t o_bc2 = alloc(64 * 4);
    size_t o_h0h = alloc((size_t)NN * 16 * 2);
    size_t o_cat = alloc((size_t)NN * 256 * 2);
    size_t o_deg = alloc((size_t)9 * NN * 4);
    size_t o_off = alloc((size_t)9 * NN * 4);
    size_t o_eid = alloc((size_t)9 * NE * 4);
    (void)ws_size; // ~91 MB total; round-0 path proved >= ~122 MB available

    float* wc0 = (float*)(ws + o_wc0); float* bc0 = (float*)(ws + o_bc0);
    float* wc1 = (float*)(ws + o_wc1); float* bc1 = (float*)(ws + o_bc1);
    f16*   b2f = (f16*)(ws + o_b2f);   float* bc2 = (float*)(ws + o_bc2);
    f16*   h0h = (f16*)(ws + o_h0h);
    f16*   cat = (f16*)(ws + o_cat);
    int*   deg = (int*)(ws + o_deg);
    int*   offp = (int*)(ws + o_off);
    int*   eid = (int*)(ws + o_eid);

    dim3 B(256);
    prep_weights<<<1, B, 0, stream>>>(W0n, W0r, b0, W1n, W1r, b1, P1, pb1,
                                      W2n, W2r, b2, P2, pb2,
                                      wc0, bc0, wc1, bc1, b2f, bc2);
    hipMemsetAsync(deg, 0, (size_t)9 * NN * 4, stream);
    hist9<<<dim3(NE / 256, 9), B, 0, stream>>>(ep, deg);
    scan9<<<9, 1024, 0, stream>>>(deg, offp);
    fill9<<<dim3(NE / 256, 9), B, 0, stream>>>(ep, offp, eid);

    t0f<<<(NN + 255) / 256, B, 0, stream>>>(x, deg, offp, eid, wc0, bc0, h0h);
    t1f<<<(NN + 255) / 256, B, 0, stream>>>(h0h, deg, offp, eid, wc1, bc1, cat);
    g2<<<dim3(NN * 8 / 256, 7), B, 0, stream>>>(deg, offp, eid, cat);
    t2<<<512, B, 0, stream>>>(cat, b2f, bc2, out);
}

// Round 3
// 1073.117 us; speedup vs baseline: 1.2520x; 1.2520x over previous
//
#include <hip/hip_runtime.h>

#define NN 100000
#define NE 800000
#define RSPAN 12500  // NN / 8 dst nodes owned per XCD slot

typedef _Float16 f16;
typedef __attribute__((ext_vector_type(4))) _Float16 f16x4;
typedef __attribute__((ext_vector_type(8))) _Float16 f16x8;
typedef __attribute__((ext_vector_type(4))) float f32x4;

struct EPtrs { const int* s[9]; const int* d[9]; };

// ---------------- prep: combined weights ----------------
__global__ __launch_bounds__(256) void prep_weights(
    const float* __restrict__ W0n, const float* __restrict__ W0r, const float* __restrict__ b0,
    const float* __restrict__ W1n, const float* __restrict__ W1r, const float* __restrict__ b1,
    const float* __restrict__ P1,  const float* __restrict__ pb1,
    const float* __restrict__ W2n, const float* __restrict__ W2r, const float* __restrict__ b2,
    const float* __restrict__ P2,  const float* __restrict__ pb2,
    float* __restrict__ wc0, float* __restrict__ bc0,
    float* __restrict__ wc1, float* __restrict__ bc1,
    f16*   __restrict__ b2frag, float* __restrict__ bc2)
{
    int tid = threadIdx.x;
    for (int t = tid; t < 18 * 16; t += 256) {
        int row = t >> 4, col = t & 15;
        float v;
        if (row < 6)       v = W0n[row * 16 + col];
        else if (row < 12) v = W0n[96 + (row - 6) * 16 + col];
        else               v = W0r[(row - 12) * 16 + col] + W0r[96 + (row - 12) * 16 + col];
        wc0[t] = v;
    }
    for (int t = tid; t < 16; t += 256) bc0[t] = b0[t] + b0[16 + t];

    for (int t = tid; t < 48 * 32; t += 256) {
        int row = t >> 5, col = t & 31;
        float v;
        if (row < 16)      v = W1n[row * 32 + col];
        else if (row < 32) v = W1n[512 + (row - 16) * 32 + col];
        else { int rr = row - 32; v = W1r[rr * 32 + col] + W1r[512 + rr * 32 + col] + P1[rr * 32 + col]; }
        wc1[t] = v;
    }
    for (int t = tid; t < 32; t += 256) bc1[t] = b1[t] + b1[32 + t] + pb1[t];

    for (int t = tid; t < 256 * 64; t += 256) {
        int j = t & 7, lane = (t >> 3) & 63, ntk = t >> 9;
        int nt = ntk & 3, kt = ntk >> 2;
        int k = kt * 32 + (lane >> 4) * 8 + j;
        int n = nt * 16 + (lane & 15);
        float v;
        if (k < 224) v = W2n[k * 64 + n];
        else {
            int rr = k - 224;
            v = P2[rr * 64 + n];
            #pragma unroll
            for (int r = 0; r < 7; ++r) v += W2r[r * 2048 + rr * 64 + n];
        }
        b2frag[t] = (f16)v;
    }
    for (int t = tid; t < 64; t += 256) {
        float v = pb2[t];
        #pragma unroll
        for (int r = 0; r < 7; ++r) v += b2[r * 64 + t];
        bc2[t] = v;
    }
}

// ---------------- CSR build, XCD-ownership filtered ----------------
// block b owns dst range [(b&7)*RSPAN, +RSPAN); blockIdx%8 tracks the XCD
// round-robin mapping so each deg/eidx cache line is written by one XCD only.
__global__ __launch_bounds__(256) void hist9x(EPtrs ep, int* __restrict__ deg)
{
    int r = blockIdx.y;
    int lo = (blockIdx.x & 7) * RSPAN, hi = lo + RSPAN;
    int e0 = (blockIdx.x >> 3) * 1024 + threadIdx.x * 4;
    int* dr = deg + r * NN;
    if (e0 + 3 < NE) {
        int4 d4 = *reinterpret_cast<const int4*>(ep.d[r] + e0);
        if (d4.x >= lo && d4.x < hi) atomicAdd(&dr[d4.x], 1);
        if (d4.y >= lo && d4.y < hi) atomicAdd(&dr[d4.y], 1);
        if (d4.z >= lo && d4.z < hi) atomicAdd(&dr[d4.z], 1);
        if (d4.w >= lo && d4.w < hi) atomicAdd(&dr[d4.w], 1);
    } else {
        for (int e = e0; e < NE; ++e) {
            int d = ep.d[r][e];
            if (d >= lo && d < hi) atomicAdd(&dr[d], 1);
        }
    }
}

__global__ __launch_bounds__(256) void fill9x(EPtrs ep, int* __restrict__ off, int* __restrict__ eidx)
{
    int r = blockIdx.y;
    int lo = (blockIdx.x & 7) * RSPAN, hi = lo + RSPAN;
    int e0 = (blockIdx.x >> 3) * 1024 + threadIdx.x * 4;
    int* offr = off + r * NN;
    int* er = eidx + (size_t)r * NE;
    if (e0 + 3 < NE) {
        int4 d4 = *reinterpret_cast<const int4*>(ep.d[r] + e0);
        int4 s4 = *reinterpret_cast<const int4*>(ep.s[r] + e0);
        if (d4.x >= lo && d4.x < hi) er[atomicAdd(&offr[d4.x], 1)] = s4.x;
        if (d4.y >= lo && d4.y < hi) er[atomicAdd(&offr[d4.y], 1)] = s4.y;
        if (d4.z >= lo && d4.z < hi) er[atomicAdd(&offr[d4.z], 1)] = s4.z;
        if (d4.w >= lo && d4.w < hi) er[atomicAdd(&offr[d4.w], 1)] = s4.w;
    } else {
        for (int e = e0; e < NE; ++e) {
            int d = ep.d[r][e];
            if (d >= lo && d < hi) er[atomicAdd(&offr[d], 1)] = ep.s[r][e];
        }
    }
}

// exclusive scan of deg -> off, one block (1024 thr) per relation
__global__ __launch_bounds__(1024) void scan9(const int* __restrict__ deg, int* __restrict__ off)
{
    int r = blockIdx.x;
    int tid = threadIdx.x, lane = tid & 63, wid = tid >> 6;
    __shared__ int woff[16];
    __shared__ int stot;
    int carry = 0;
    for (int base = 0; base < NN; base += 1024) {
        int i = base + tid;
        int v = (i < NN) ? deg[r * NN + i] : 0;
        int incl = v;
        #pragma unroll
        for (int ofs = 1; ofs < 64; ofs <<= 1) {
            int t = __shfl_up(incl, ofs, 64);
            if (lane >= ofs) incl += t;
        }
        if (lane == 63) woff[wid] = incl;
        __syncthreads();
        if (tid < 16) {
            int wv = woff[tid];
            int winc = wv;
            #pragma unroll
            for (int ofs = 1; ofs < 16; ofs <<= 1) {
                int t = __shfl_up(winc, ofs, 64);
                if (tid >= ofs) winc += t;
            }
            woff[tid] = winc - wv;
            if (tid == 15) stot = winc;
        }
        __syncthreads();
        int excl = incl - v + woff[wid] + carry;
        if (i < NN) off[r * NN + i] = excl;
        carry += stot;
        __syncthreads();
    }
}

// ---------------- layer 0 fused gather+transform: x(6) -> h0h(16 f16) ----------------
__global__ __launch_bounds__(256) void t0f(const float* __restrict__ x,
                                           const int* __restrict__ deg, const int* __restrict__ off,
                                           const int* __restrict__ eidx,
                                           const float* __restrict__ wc0, const float* __restrict__ bc0,
                                           f16* __restrict__ h0h)
{
    __shared__ float sw[288 + 16];
    for (int t = threadIdx.x; t < 304; t += 256) sw[t] = (t < 288) ? wc0[t] : bc0[t - 288];
    __syncthreads();
    int n = blockIdx.x * 256 + threadIdx.x;
    if (n >= NN) return;
    float acc[16];
    #pragma unroll
    for (int j = 0; j < 16; ++j) acc[j] = sw[288 + j];
    float xv[6];
    {
        const float2* xp = reinterpret_cast<const float2*>(x + (size_t)n * 6);
        float2 a = xp[0], b = xp[1], c = xp[2];
        xv[0] = a.x; xv[1] = a.y; xv[2] = b.x; xv[3] = b.y; xv[4] = c.x; xv[5] = c.y;
    }
    #pragma unroll
    for (int r = 0; r < 2; ++r) {
        float m[6] = {0, 0, 0, 0, 0, 0};
        int e1 = off[r * NN + n];
        int e0 = e1 - deg[r * NN + n];
        for (int e = e0; e < e1; ++e) {
            int s = eidx[(size_t)r * NE + e];
            const float2* sp = reinterpret_cast<const float2*>(x + (size_t)s * 6);
            float2 a = sp[0], b = sp[1], c = sp[2];
            m[0] += a.x; m[1] += a.y; m[2] += b.x; m[3] += b.y; m[4] += c.x; m[5] += c.y;
        }
        #pragma unroll
        for (int k = 0; k < 6; ++k) {
            float s = m[k];
            #pragma unroll
            for (int j = 0; j < 16; ++j) acc[j] = fmaf(s, sw[(r * 6 + k) * 16 + j], acc[j]);
        }
    }
    #pragma unroll
    for (int k = 0; k < 6; ++k) {
        float s = xv[k];
        #pragma unroll
        for (int j = 0; j < 16; ++j) acc[j] = fmaf(s, sw[(12 + k) * 16 + j], acc[j]);
    }
    f16x8 o0, o1;
    #pragma unroll
    for (int j = 0; j < 8; ++j) { o0[j] = (f16)acc[j]; o1[j] = (f16)acc[8 + j]; }
    f16x8* op = reinterpret_cast<f16x8*>(h0h + (size_t)n * 16);
    op[0] = o0; op[1] = o1;
}

// ---------------- layer 1 fused: h0h(16) -> h1 (f16, into m2cat slot 224) ----------------
__global__ __launch_bounds__(256) void t1f(const f16* __restrict__ h0h,
                                           const int* __restrict__ deg, const int* __restrict__ off,
                                           const int* __restrict__ eidx,
                                           const float* __restrict__ wc1, const float* __restrict__ bc1,
                                           f16* __restrict__ m2cat)
{
    __shared__ float sw[1536 + 32];
    for (int t = threadIdx.x; t < 1568; t += 256) sw[t] = (t < 1536) ? wc1[t] : bc1[t - 1536];
    __syncthreads();
    int n = blockIdx.x * 256 + threadIdx.x;
    if (n >= NN) return;
    float acc[32];
    #pragma unroll
    for (int j = 0; j < 32; ++j) acc[j] = sw[1536 + j];
    #pragma unroll
    for (int r = 0; r < 2; ++r) {
        float m[16];
        #pragma unroll
        for (int k = 0; k < 16; ++k) m[k] = 0.f;
        int e1 = off[r * NN + n];
        int e0 = e1 - deg[r * NN + n];
        for (int e = e0; e < e1; ++e) {
            int s = eidx[(size_t)r * NE + e];
            const f16x8* sp = reinterpret_cast<const f16x8*>(h0h + (size_t)s * 16);
            f16x8 a = sp[0], b = sp[1];
            #pragma unroll
            for (int k = 0; k < 8; ++k) { m[k] += (float)a[k]; m[8 + k] += (float)b[k]; }
        }
        #pragma unroll
        for (int k = 0; k < 16; ++k) {
            float s = m[k];
            #pragma unroll
            for (int j = 0; j < 32; ++j) acc[j] = fmaf(s, sw[(r * 16 + k) * 32 + j], acc[j]);
        }
    }
    {
        const f16x8* hp = reinterpret_cast<const f16x8*>(h0h + (size_t)n * 16);
        f16x8 a = hp[0], b = hp[1];
        #pragma unroll
        for (int k = 0; k < 8; ++k) {
            float s0 = (float)a[k], s1 = (float)b[k];
            #pragma unroll
            for (int j = 0; j < 32; ++j)
                acc[j] = fmaf(s0, sw[(32 + k) * 32 + j], fmaf(s1, sw[(40 + k) * 32 + j], acc[j]));
        }
    }
    f16x8* op = reinterpret_cast<f16x8*>(m2cat + (size_t)n * 256 + 224);
    #pragma unroll
    for (int q = 0; q < 4; ++q) {
        f16x8 o;
        #pragma unroll
        for (int j = 0; j < 8; ++j) o[j] = (f16)fmaxf(acc[q * 8 + j], 0.f);
        op[q] = o;
    }
}

// ---------------- layer 2 gather: 8 lanes/node, h1 slots -> msg slots of m2cat ----------------
__global__ __launch_bounds__(256) void g2(const int* __restrict__ deg, const int* __restrict__ off,
                                          const int* __restrict__ eidx, f16* __restrict__ m2cat)
{
    int r = blockIdx.y;                         // 0..6 -> edge list r+2
    int t = blockIdx.x * 256 + threadIdx.x;     // 3125*256 == NN*8 exactly
    int node = t >> 3, l = t & 7;
    int L = r + 2;
    int d = deg[L * NN + node];
    int e1 = off[L * NN + node];
    int e0 = e1 - d;
    float a0 = 0.f, a1 = 0.f, a2 = 0.f, a3 = 0.f;
    for (int e = e0; e < e1; ++e) {
        int s = eidx[(size_t)L * NE + e];
        f16x4 v = *reinterpret_cast<const f16x4*>(m2cat + (size_t)s * 256 + 224 + l * 4);
        a0 += (float)v[0]; a1 += (float)v[1]; a2 += (float)v[2]; a3 += (float)v[3];
    }
    float sc = (r == 2 || r == 3 || r == 6) ? (1.0f / (float)max(d, 1)) : 1.0f;
    f16x4 o;
    o[0] = (f16)(a0 * sc); o[1] = (f16)(a1 * sc); o[2] = (f16)(a2 * sc); o[3] = (f16)(a3 * sc);
    *reinterpret_cast<f16x4*>(m2cat + (size_t)node * 256 + r * 32 + l * 4) = o;
}

// ---------------- layer 2 transform: MFMA GEMM [100000x256] x [256x64] + bias, relu ----------------
__global__ __launch_bounds__(256) void t2(const f16* __restrict__ m2cat, const f16* __restrict__ b2frag,
                                          const float* __restrict__ bc2, float* __restrict__ out)
{
    int lane = threadIdx.x & 63;
    int gw = blockIdx.x * 4 + (threadIdx.x >> 6);
    int NW = gridDim.x * 4;
    int quad = lane >> 4, col0 = lane & 15;

    f16x8 bf[32];
    #pragma unroll
    for (int i = 0; i < 32; ++i)
        bf[i] = *reinterpret_cast<const f16x8*>(b2frag + ((size_t)i * 64 + lane) * 8);
    float bcv[4];
    #pragma unroll
    for (int nt = 0; nt < 4; ++nt) bcv[nt] = bc2[nt * 16 + col0];

    for (int mt = gw; mt < NN / 16; mt += NW) {
        const f16* arow = m2cat + ((size_t)(mt * 16 + col0)) * 256 + quad * 8;
        f16x8 af[8];
        #pragma unroll
        for (int kt = 0; kt < 8; ++kt)
            af[kt] = *reinterpret_cast<const f16x8*>(arow + kt * 32);
        f32x4 acc[4];
        #pragma unroll
        for (int nt = 0; nt < 4; ++nt) acc[nt] = (f32x4){0.f, 0.f, 0.f, 0.f};
        #pragma unroll
        for (int kt = 0; kt < 8; ++kt) {
            #pragma unroll
            for (int nt = 0; nt < 4; ++nt)
                acc[nt] = __builtin_amdgcn_mfma_f32_16x16x32_f16(af[kt], bf[kt * 4 + nt], acc[nt], 0, 0, 0);
        }
        #pragma unroll
        for (int nt = 0; nt < 4; ++nt) {
            #pragma unroll
            for (int i = 0; i < 4; ++i) {
                int row = mt * 16 + quad * 4 + i;
                out[(size_t)row * 64 + nt * 16 + col0] = fmaxf(acc[nt][i] + bcv[nt], 0.f);
            }
        }
    }
}

// ---------------- launch ----------------
extern "C" void kernel_launch(void* const* d_in, const int* in_sizes, int n_in,
                              void* d_out, int out_size, void* d_ws, size_t ws_size,
                              hipStream_t stream)
{
    const float* x = (const float*)d_in[0];
    EPtrs ep;
    for (int i = 0; i < 9; ++i) { const int* p = (const int*)d_in[1 + i]; ep.s[i] = p; ep.d[i] = p + NE; }
    const float* W0n = (const float*)d_in[10]; const float* W0r = (const float*)d_in[11];
    const float* b0  = (const float*)d_in[12];
    const float* W1n = (const float*)d_in[13]; const float* W1r = (const float*)d_in[14];
    const float* b1  = (const float*)d_in[15];
    const float* P1  = (const float*)d_in[16]; const float* pb1 = (const float*)d_in[17];
    const float* W2n = (const float*)d_in[18]; const float* W2r = (const float*)d_in[19];
    const float* b2  = (const float*)d_in[20];
    const float* P2  = (const float*)d_in[21]; const float* pb2 = (const float*)d_in[22];
    float* out = (float*)d_out;
    char* ws = (char*)d_ws;

    size_t off_b = 0;
    auto alloc = [&](size_t b) { size_t o = off_b; off_b += (b + 255) & ~(size_t)255; return o; };
    size_t o_wc0 = alloc(288 * 4);   size_t o_bc0 = alloc(16 * 4);
    size_t o_wc1 = alloc(1536 * 4);  size_t o_bc1 = alloc(32 * 4);
    size_t o_b2f = alloc(16384 * 2); size_t o_bc2 = alloc(64 * 4);
    size_t o_h0h = alloc((size_t)NN * 16 * 2);
    size_t o_cat = alloc((size_t)NN * 256 * 2);
    size_t o_deg = alloc((size_t)9 * NN * 4);
    size_t o_off = alloc((size_t)9 * NN * 4);
    size_t o_eid = alloc((size_t)9 * NE * 4);
    (void)ws_size;

    float* wc0 = (float*)(ws + o_wc0); float* bc0 = (float*)(ws + o_bc0);
    float* wc1 = (float*)(ws + o_wc1); float* bc1 = (float*)(ws + o_bc1);
    f16*   b2f = (f16*)(ws + o_b2f);   float* bc2 = (float*)(ws + o_bc2);
    f16*   h0h = (f16*)(ws + o_h0h);
    f16*   cat = (f16*)(ws + o_cat);
    int*   deg = (int*)(ws + o_deg);
    int*   offp = (int*)(ws + o_off);
    int*   eid = (int*)(ws + o_eid);

    dim3 B(256);
    const int NCHUNK = (NE + 1023) / 1024;  // 782
    prep_weights<<<1, B, 0, stream>>>(W0n, W0r, b0, W1n, W1r, b1, P1, pb1,
                                      W2n, W2r, b2, P2, pb2,
                                      wc0, bc0, wc1, bc1, b2f, bc2);
    hipMemsetAsync(deg, 0, (size_t)9 * NN * 4, stream);
    hist9x<<<dim3(8 * NCHUNK, 9), B, 0, stream>>>(ep, deg);
    scan9<<<9, 1024, 0, stream>>>(deg, offp);
    fill9x<<<dim3(8 * NCHUNK, 9), B, 0, stream>>>(ep, offp, eid);

    t0f<<<(NN + 255) / 256, B, 0, stream>>>(x, deg, offp, eid, wc0, bc0, h0h);
    t1f<<<(NN + 255) / 256, B, 0, stream>>>(h0h, deg, offp, eid, wc1, bc1, cat);
    g2<<<dim3(NN * 8 / 256, 7), B, 0, stream>>>(deg, offp, eid, cat);
    t2<<<512, B, 0, stream>>>(cat, b2f, bc2, out);
}